// Round 5
// baseline (169.821 us; speedup 1.0000x reference)
//
#include <hip/hip_runtime.h>
#include <hip/hip_bf16.h>
#include <math.h>

#define M_ROWS 65536
#define NSPLINE 32
#define BM 32            // rows per block (2 row-halves x 16)
#define WROWS 16         // rows per wave
#define GROUP 4          // splines per iteration (one per quad q)
#define NGRP 4           // group-iterations per wave (16 splines/wave)
#define NITER 8          // total groups (2 waves' worth)
#define NTILE 9          // ceil(33 params / 4-per-lane) MFMA tiles per group
#define WB_ELEMS (NITER * NTILE * 2 * 64 * 8)   // 73728 fp16 = 144 KiB

typedef __attribute__((ext_vector_type(8))) _Float16 half8;
typedef __attribute__((ext_vector_type(4))) float floatx4;

// R8/R10-proven poly softplus (full-rate FMA path; fallback wave-divergence
// is rare). R13 proved the 2-transcendental "branchless" version costs more
// (trans pipe is 1/4 rate), so keep the polynomial.
__device__ __forceinline__ float softplus_fast(float t) {
    float u = t * t;
    if (u > 1.21f) return log1pf(__expf(t));   // rare, exact
    float p = fmaf(u, -2.6352e-5f, 3.4722222e-4f);
    p = fmaf(u, p, -5.2083333e-3f);
    p = fmaf(u, p, 0.125f);
    p = fmaf(u, p, 0.69314718f);
    return fmaf(t, 0.5f, p);
}

// ---------------------------------------------------------------------------
// R14-proven pack: transpose lives at pack time. m-mapping per tile tau:
//   m = (spline-sub q_m)*4 + r  ->  column (spline = g*4+q_m, param = tau*4+r)
// MFMA D-layout (m=(lane>>4)*4+reg, n=lane&15) lands param tau*4+r of spline
// g*4+q directly in lane (q,cc)'s accumulator. A-fragment element layout:
//   lane L, elem j: m = L&15, k = half*32 + (L>>4)*8 + j
//   k<48: W[k][col]; k==48: bias (paired with B=1.0); else 0.
// ---------------------------------------------------------------------------
__global__ void pack_W(const float* __restrict__ W, const float* __restrict__ b,
                       _Float16* __restrict__ WH) {
    int idx = blockIdx.x * 256 + threadIdx.x;     // < 73728
    int j    = idx & 7;
    int lane = (idx >> 3) & 63;
    int half = (idx >> 9) & 1;
    int tile = idx >> 10;        // 0..71 = g*NTILE + tau
    int tau  = tile % NTILE;
    int g    = tile / NTILE;
    int m  = lane & 15;
    int k  = half * 32 + ((lane >> 4) << 3) + j;
    int spline = g * 4 + (m >> 2);
    int param  = tau * 4 + (m & 3);
    float v = 0.0f;
    if (param < 33 && k <= 48) {
        int col = spline * 33 + param;
        v = (k < 48) ? W[k * 1056 + col] : b[col];
    }
    WH[idx] = (_Float16)v;
}

// pv[p] lives in the MFMA accumulators; indices are all compile-time.
#define PV(p) (acc[(p) >> 2][(p) & 3])

// ---------------------------------------------------------------------------
// R15: GRID-DOUBLING. R14's counters showed the occupancy cap is the GRID:
// 1024 blocks x 4 waves = 4096 waves vs 8192 machine slots (VGPR=48, LDS=0
// -> HW could host 8 waves/SIMD, we offered 2; OccupancyPercent 31, VALU
// idle ~half on WH-load latency + serial spline chains). Split the 32
// splines across 2 waves: each wave = 16 rows x 16 splines (4 groups).
// Block = 4 waves = {row-half rh} x {spline-half s} over BM=32 rows; grid =
// 2048 blocks = 8192 waves = 100% of slots. Total traffic unchanged. Only
// new coupling: logdet row-sum spans the two spline-halves -> 256 B LDS +
// one __syncthreads + one add. launch_bounds(256,8) pins VGPR <= 64.
// ---------------------------------------------------------------------------
__global__ void __launch_bounds__(256, 8) fused_kernel(
    const float* __restrict__ z, const float* __restrict__ c,
    const _Float16* __restrict__ WH, float* __restrict__ out)
{
    __shared__ float lds_ld[4][16];    // per-wave logdet halves

    const int tid  = threadIdx.x;
    const int w    = tid >> 6;
    const int rh   = w >> 1;           // row-half within block
    const int s    = w & 1;            // spline-half (groups s*4 .. s*4+3)
    const int lane = tid & 63;
    const int q    = lane >> 4;        // quad 0..3 = spline-sub within group
    const int cc   = lane & 15;        // row within wave
    const int row_base = blockIdx.x * BM + rh * WROWS;

    // ---- z2 passthrough: out[:, :32] = z[:, 32:64], 32 rows, 1 f4/thread --
    {
        int rr = blockIdx.x * BM + (tid >> 3);
        int v4 = tid & 7;
        float4 val = *(const float4*)(z + (size_t)rr * 64 + 32 + v4 * 4);
        *(float4*)(out + (size_t)rr * 64 + v4 * 4) = val;
    }

    // ---- z2c fragments (fp16, persist): the B operand ---------------------
    // B[k=(q*8+j)][n=cc] = z2c[row cc][k]
    half8 a0, a1;
    {
        const float* zr = z + (size_t)(row_base + cc) * 64 + 32;
        float4 v0 = *(const float4*)(zr + q * 8);
        float4 v1 = *(const float4*)(zr + q * 8 + 4);
        a0[0]=(_Float16)v0.x; a0[1]=(_Float16)v0.y;
        a0[2]=(_Float16)v0.z; a0[3]=(_Float16)v0.w;
        a0[4]=(_Float16)v1.x; a0[5]=(_Float16)v1.y;
        a0[6]=(_Float16)v1.z; a0[7]=(_Float16)v1.w;
        if (q < 2) {
            const float* cr = c + (size_t)(row_base + cc) * 16 + q * 8;
            float4 u0 = *(const float4*)cr;
            float4 u1 = *(const float4*)(cr + 4);
            a1[0]=(_Float16)u0.x; a1[1]=(_Float16)u0.y;
            a1[2]=(_Float16)u0.z; a1[3]=(_Float16)u0.w;
            a1[4]=(_Float16)u1.x; a1[5]=(_Float16)u1.y;
            a1[6]=(_Float16)u1.z; a1[7]=(_Float16)u1.w;
        } else {
            #pragma unroll
            for (int j = 0; j < 8; ++j) a1[j] = (_Float16)0.0f;
            if (q == 2) a1[0] = (_Float16)1.0f;   // k=48 bias row
        }
    }

    // z1 base for this lane's spline inputs: z[row cc][n = g*4 + q]
    const float* z1p = z + (size_t)(row_base + cc) * 64 + q;

    float ld_acc = 0.0f;

    #pragma unroll 1
    for (int g2 = 0; g2 < NGRP; ++g2) {
        const int g = s * NGRP + g2;        // this wave's group
        const float in = z1p[g * 4];        // hot L1 line

        // ---- GEMM: 9 tiles x (K=32 + K=16+bias) -> pv in registers --------
        floatx4 acc[NTILE];
        const half8* base = (const half8*)WH + (size_t)g * (NTILE * 2 * 64) + lane;
        #pragma unroll
        for (int t = 0; t < NTILE; ++t) {
            half8 w0 = base[(t * 2 + 0) * 64];
            half8 w1 = base[(t * 2 + 1) * 64];
            floatx4 a = {0.f, 0.f, 0.f, 0.f};
            a = __builtin_amdgcn_mfma_f32_16x16x32_f16(w0, a0, a, 0, 0, 0);
            a = __builtin_amdgcn_mfma_f32_16x16x32_f16(w1, a1, a, 0, 0, 0);
            acc[t] = a;
        }
        // lane (q,cc) now holds PV(p) = y[row cc][spline g*4+q][param p].

        // ---- spline on registers -----------------------------------------
        const int n = g * GROUP + q;

        float wd[16];
        float sew = 0.f;
        #pragma unroll
        for (int i = 0; i < 16; ++i) {
            float e = __expf(PV(17 + i));
            wd[i] = e; sew += e;
        }
        const float inv_sew = 0.984f * __builtin_amdgcn_rcpf(sew);
        #pragma unroll
        for (int i = 0; i < 16; ++i) wd[i] = 0.001f + wd[i] * inv_sew;

        float h[17];
        #pragma unroll
        for (int i = 0; i < 17; ++i)
            h[i] = softplus_fast(PV(i)) + 0.001f;

        float area = 0.f;
        #pragma unroll
        for (int i = 0; i < 16; ++i) area += (h[i] + h[i + 1]) * 0.5f * wd[i];
        const float inv_area = 0.999f * __builtin_amdgcn_rcpf(area);
        #pragma unroll
        for (int i = 0; i < 17; ++i) h[i] = 0.001f + h[i] * inv_area;

        float loc = 0.f, cdfl = 0.f;
        float sel_loc = 0.f, sel_w = wd[0], sel_cdf = 0.f;
        float sel_lh = h[0], sel_rh = h[1];
        #pragma unroll
        for (int bn = 1; bn < 16; ++bn) {
            cdfl = fmaf((h[bn - 1] + h[bn]) * 0.5f, wd[bn - 1], cdfl);
            loc += wd[bn - 1];
            if (in >= loc) {                        // monotone: last true wins
                sel_loc = loc; sel_w = wd[bn]; sel_cdf = cdfl;
                sel_lh = h[bn]; sel_rh = h[bn + 1];
            }
        }

        const float alpha = (in - sel_loc) * __builtin_amdgcn_rcpf(sel_w);
        const float dh    = sel_rh - sel_lh;
        float o = ((0.5f * dh * sel_w) * alpha + sel_lh * sel_w) * alpha + sel_cdf;
        o = fminf(fmaxf(o, 0.0f), 1.0f);
        out[(size_t)(row_base + cc) * 64 + 32 + n] = o;
        ld_acc += __logf(fmaf(alpha, dh, sel_lh));
    }

    // ---- logdet: reduce q-partials within wave, then spline-halves via LDS
    ld_acc += __shfl_down(ld_acc, 32, 64);
    ld_acc += __shfl_down(ld_acc, 16, 64);
    if (q == 0) lds_ld[w][cc] = ld_acc;            // row cc's half-sum
    __syncthreads();
    if (s == 0 && q == 0)
        out[(size_t)M_ROWS * 64 + row_base + cc] = ld_acc + lds_ld[w + 1][cc];

    // (w and w+1 share row_base when s==0; w+1 holds splines 16..31.)
}

extern "C" void kernel_launch(void* const* d_in, const int* in_sizes, int n_in,
                              void* d_out, int out_size, void* d_ws, size_t ws_size,
                              hipStream_t stream) {
    const float* c = (const float*)d_in[0];   // (M, 16)
    const float* z = (const float*)d_in[1];   // (M, 64)
    const float* W = (const float*)d_in[2];   // (48, 1056)
    const float* b = (const float*)d_in[3];   // (1056,)
    float* out = (float*)d_out;               // M*64 (x) then M (logdet)
    _Float16* WH = (_Float16*)d_ws;           // 73728 fp16 = 144 KiB

    pack_W<<<WB_ELEMS / 256, 256, 0, stream>>>(W, b, WH);
    fused_kernel<<<M_ROWS / BM, 256, 0, stream>>>(z, c, WH, out);
}

// Round 6
// 113.948 us; speedup vs baseline: 1.4903x; 1.4903x over previous
//
#include <hip/hip_runtime.h>
#include <hip/hip_bf16.h>
#include <math.h>

#define M_ROWS 65536
#define NSPLINE 32
#define BM 32            // rows per block (2 row-halves x 16)
#define WROWS 16         // rows per wave
#define GROUP 4          // splines per iteration (one per quad q)
#define NGRP 4           // group-iterations per wave (16 splines/wave)
#define NITER 8          // total groups (2 waves' worth)
#define NTILE 9          // ceil(33 params / 4-per-lane) MFMA tiles per group
#define WB_ELEMS (NITER * NTILE * 2 * 64 * 8)   // 73728 fp16 = 144 KiB

typedef __attribute__((ext_vector_type(8))) _Float16 half8;
typedef __attribute__((ext_vector_type(4))) float floatx4;

// R8/R10-proven poly softplus (full-rate FMA path; fallback wave-divergence
// is rare). R13 proved the 2-transcendental branchless version costs more.
__device__ __forceinline__ float softplus_fast(float t) {
    float u = t * t;
    if (u > 1.21f) return log1pf(__expf(t));   // rare, exact
    float p = fmaf(u, -2.6352e-5f, 3.4722222e-4f);
    p = fmaf(u, p, -5.2083333e-3f);
    p = fmaf(u, p, 0.125f);
    p = fmaf(u, p, 0.69314718f);
    return fmaf(t, 0.5f, p);
}

// ---------------------------------------------------------------------------
// R14-proven pack: transpose lives at pack time. m-mapping per tile tau:
//   m = (spline-sub q_m)*4 + r  ->  column (spline = g*4+q_m, param = tau*4+r)
// MFMA D-layout (m=(lane>>4)*4+reg, n=lane&15) lands param tau*4+r of spline
// g*4+q directly in lane (q,cc)'s accumulator. A-fragment element layout:
//   lane L, elem j: m = L&15, k = half*32 + (L>>4)*8 + j
//   k<48: W[k][col]; k==48: bias (paired with B=1.0); else 0.
// ---------------------------------------------------------------------------
__global__ void pack_W(const float* __restrict__ W, const float* __restrict__ b,
                       _Float16* __restrict__ WH) {
    int idx = blockIdx.x * 256 + threadIdx.x;     // < 73728
    int j    = idx & 7;
    int lane = (idx >> 3) & 63;
    int half = (idx >> 9) & 1;
    int tile = idx >> 10;        // 0..71 = g*NTILE + tau
    int tau  = tile % NTILE;
    int g    = tile / NTILE;
    int m  = lane & 15;
    int k  = half * 32 + ((lane >> 4) << 3) + j;
    int spline = g * 4 + (m >> 2);
    int param  = tau * 4 + (m & 3);
    float v = 0.0f;
    if (param < 33 && k <= 48) {
        int col = spline * 33 + param;
        v = (k < 48) ? W[k * 1056 + col] : b[col];
    }
    WH[idx] = (_Float16)v;
}

// Phase-1 accumulators hold params 16..35 (tiles 4..8); phase-2 params 0..15.
#define PVW(p) (accW[((p) - 16) >> 2][((p) - 16) & 3])   // p in 16..32
#define PVH(p) (accH[(p) >> 2][(p) & 3])                 // p in 0..15

// ---------------------------------------------------------------------------
// R16 = R15's decomposition (16 rows x 16 splines per wave; 2048 blocks =
// 8192 waves = 100% of machine slots) with the spill fixed:
//  (1) NO waves-per-EU floor. R15's (256,8) forced VGPR=32 -> scratch spill
//      -> FETCH/WRITE both ~11x (scratch traffic), dur 102us. This is the
//      R6/R7 lesson the R10 comments recorded; violated once, now proven.
//  (2) Two-phase GEMM to drop natural pressure under the 64-VGPR/8-wave
//      threshold: tiles 4..8 (params 16..32) -> wd[] + h[16] extraction
//      frees 20 acc slots BEFORE tiles 0..3 (params 0..15) -> h[0..15].
//      Values identical (independent sub-computations reordered).
// ---------------------------------------------------------------------------
__global__ void __launch_bounds__(256) fused_kernel(
    const float* __restrict__ z, const float* __restrict__ c,
    const _Float16* __restrict__ WH, float* __restrict__ out)
{
    __shared__ float lds_ld[4][16];    // per-wave logdet halves

    const int tid  = threadIdx.x;
    const int w    = tid >> 6;
    const int rh   = w >> 1;           // row-half within block
    const int s    = w & 1;            // spline-half (groups s*4 .. s*4+3)
    const int lane = tid & 63;
    const int q    = lane >> 4;        // quad 0..3 = spline-sub within group
    const int cc   = lane & 15;        // row within wave
    const int row_base = blockIdx.x * BM + rh * WROWS;

    // ---- z2 passthrough: out[:, :32] = z[:, 32:64], 32 rows, 1 f4/thread --
    {
        int rr = blockIdx.x * BM + (tid >> 3);
        int v4 = tid & 7;
        float4 val = *(const float4*)(z + (size_t)rr * 64 + 32 + v4 * 4);
        *(float4*)(out + (size_t)rr * 64 + v4 * 4) = val;
    }

    // ---- z2c fragments (fp16, persist): the B operand ---------------------
    // B[k=(q*8+j)][n=cc] = z2c[row cc][k]
    half8 a0, a1;
    {
        const float* zr = z + (size_t)(row_base + cc) * 64 + 32;
        float4 v0 = *(const float4*)(zr + q * 8);
        float4 v1 = *(const float4*)(zr + q * 8 + 4);
        a0[0]=(_Float16)v0.x; a0[1]=(_Float16)v0.y;
        a0[2]=(_Float16)v0.z; a0[3]=(_Float16)v0.w;
        a0[4]=(_Float16)v1.x; a0[5]=(_Float16)v1.y;
        a0[6]=(_Float16)v1.z; a0[7]=(_Float16)v1.w;
        if (q < 2) {
            const float* cr = c + (size_t)(row_base + cc) * 16 + q * 8;
            float4 u0 = *(const float4*)cr;
            float4 u1 = *(const float4*)(cr + 4);
            a1[0]=(_Float16)u0.x; a1[1]=(_Float16)u0.y;
            a1[2]=(_Float16)u0.z; a1[3]=(_Float16)u0.w;
            a1[4]=(_Float16)u1.x; a1[5]=(_Float16)u1.y;
            a1[6]=(_Float16)u1.z; a1[7]=(_Float16)u1.w;
        } else {
            #pragma unroll
            for (int j = 0; j < 8; ++j) a1[j] = (_Float16)0.0f;
            if (q == 2) a1[0] = (_Float16)1.0f;   // k=48 bias row
        }
    }

    // z1 base for this lane's spline inputs: z[row cc][n = g*4 + q]
    const float* z1p = z + (size_t)(row_base + cc) * 64 + q;

    float ld_acc = 0.0f;

    #pragma unroll 1
    for (int g2 = 0; g2 < NGRP; ++g2) {
        const int g = s * NGRP + g2;        // this wave's group
        const float in = z1p[g * 4];        // hot L1 line

        const half8* base = (const half8*)WH + (size_t)g * (NTILE * 2 * 64) + lane;

        // ---- GEMM phase 1: tiles 4..8 -> params 16..32 --------------------
        floatx4 accW[5];
        #pragma unroll
        for (int t = 0; t < 5; ++t) {
            half8 w0 = base[((t + 4) * 2 + 0) * 64];
            half8 w1 = base[((t + 4) * 2 + 1) * 64];
            floatx4 a = {0.f, 0.f, 0.f, 0.f};
            a = __builtin_amdgcn_mfma_f32_16x16x32_f16(w0, a0, a, 0, 0, 0);
            a = __builtin_amdgcn_mfma_f32_16x16x32_f16(w1, a1, a, 0, 0, 0);
            accW[t] = a;
        }

        // ---- widths from params 17..32; h[16] from param 16 ---------------
        float wd[16];
        float sew = 0.f;
        #pragma unroll
        for (int i = 0; i < 16; ++i) {
            float e = __expf(PVW(17 + i));
            wd[i] = e; sew += e;
        }
        const float inv_sew = 0.984f * __builtin_amdgcn_rcpf(sew);
        #pragma unroll
        for (int i = 0; i < 16; ++i) wd[i] = 0.001f + wd[i] * inv_sew;

        float h[17];
        h[16] = softplus_fast(PVW(16)) + 0.001f;   // accW fully dead after this

        // ---- GEMM phase 2: tiles 0..3 -> params 0..15 ---------------------
        floatx4 accH[4];
        #pragma unroll
        for (int t = 0; t < 4; ++t) {
            half8 w0 = base[(t * 2 + 0) * 64];
            half8 w1 = base[(t * 2 + 1) * 64];
            floatx4 a = {0.f, 0.f, 0.f, 0.f};
            a = __builtin_amdgcn_mfma_f32_16x16x32_f16(w0, a0, a, 0, 0, 0);
            a = __builtin_amdgcn_mfma_f32_16x16x32_f16(w1, a1, a, 0, 0, 0);
            accH[t] = a;
        }
        #pragma unroll
        for (int i = 0; i < 16; ++i)
            h[i] = softplus_fast(PVH(i)) + 0.001f;

        // ---- area normalize ----------------------------------------------
        float area = 0.f;
        #pragma unroll
        for (int i = 0; i < 16; ++i) area += (h[i] + h[i + 1]) * 0.5f * wd[i];
        const float inv_area = 0.999f * __builtin_amdgcn_rcpf(area);
        #pragma unroll
        for (int i = 0; i < 17; ++i) h[i] = 0.001f + h[i] * inv_area;

        // ---- bin select (monotone scan: last true wins) -------------------
        float loc = 0.f, cdfl = 0.f;
        float sel_loc = 0.f, sel_w = wd[0], sel_cdf = 0.f;
        float sel_lh = h[0], sel_rh = h[1];
        #pragma unroll
        for (int bn = 1; bn < 16; ++bn) {
            cdfl = fmaf((h[bn - 1] + h[bn]) * 0.5f, wd[bn - 1], cdfl);
            loc += wd[bn - 1];
            if (in >= loc) {
                sel_loc = loc; sel_w = wd[bn]; sel_cdf = cdfl;
                sel_lh = h[bn]; sel_rh = h[bn + 1];
            }
        }

        const float alpha = (in - sel_loc) * __builtin_amdgcn_rcpf(sel_w);
        const float dh    = sel_rh - sel_lh;
        float o = ((0.5f * dh * sel_w) * alpha + sel_lh * sel_w) * alpha + sel_cdf;
        o = fminf(fmaxf(o, 0.0f), 1.0f);
        const int n = g * GROUP + q;
        out[(size_t)(row_base + cc) * 64 + 32 + n] = o;
        ld_acc += __logf(fmaf(alpha, dh, sel_lh));
    }

    // ---- logdet: reduce q-partials within wave, then spline-halves via LDS
    ld_acc += __shfl_down(ld_acc, 32, 64);
    ld_acc += __shfl_down(ld_acc, 16, 64);
    if (q == 0) lds_ld[w][cc] = ld_acc;            // row cc's half-sum
    __syncthreads();
    if (s == 0 && q == 0)
        out[(size_t)M_ROWS * 64 + row_base + cc] = ld_acc + lds_ld[w + 1][cc];
    // (w and w+1 share row_base when s==0; w+1 holds splines 16..31.)
}

extern "C" void kernel_launch(void* const* d_in, const int* in_sizes, int n_in,
                              void* d_out, int out_size, void* d_ws, size_t ws_size,
                              hipStream_t stream) {
    const float* c = (const float*)d_in[0];   // (M, 16)
    const float* z = (const float*)d_in[1];   // (M, 64)
    const float* W = (const float*)d_in[2];   // (48, 1056)
    const float* b = (const float*)d_in[3];   // (1056,)
    float* out = (float*)d_out;               // M*64 (x) then M (logdet)
    _Float16* WH = (_Float16*)d_ws;           // 73728 fp16 = 144 KiB

    pack_W<<<WB_ELEMS / 256, 256, 0, stream>>>(W, b, WH);
    fused_kernel<<<M_ROWS / BM, 256, 0, stream>>>(z, c, WH, out);
}